// Round 2
// baseline (58833.441 us; speedup 1.0000x reference)
//
#include <hip/hip_runtime.h>
#include <math.h>

#define Tt 512
#define Dd 768
#define Hh 512
#define Bb 32
#define G3 1536
#define HB (Hh*Bb)
#define RB 128            // row-blocks: 4 rows per gate-group each (128*4 = 512)
#define NBLK 192          // 128 row + 32 m0-tail + 32 m1-chain (64 spare CUs: straggler immunity)
#define NTHR 512
#define NGRP 12           // 192 blocks = 12 groups x 16
#define NBAR (Tt*3)       // 3 grid barriers per step (structural floor: cell0->cell1->cell2)
#define PR 32             // state ring period (staleness window; L2 churn evicts 32-step-old lines)

__device__ __forceinline__ float sigf(float x) { return 1.f / (1.f + expf(-x)); }

__device__ __forceinline__ float dot4f(const float4 w4, const float* v) {
  return w4.x*v[0] + w4.y*v[1] + w4.z*v[2] + w4.w*v[3];
}

// device-scope write-through store: lands at coherence point (MALL), no fence needed
__device__ __forceinline__ void dstore(float* p, float v) {
  __hip_atomic_store(p, v, __ATOMIC_RELAXED, __HIP_MEMORY_SCOPE_AGENT);
}
__device__ __forceinline__ float dload(const float* p) {
  return __hip_atomic_load(p, __ATOMIC_RELAXED, __HIP_MEMORY_SCOPE_AGENT);
}

// ---------------- grid barrier: relaxed monotone atomics, two-level tree ----
// __syncthreads() emits s_waitcnt vmcnt(0) per wave => all device-scope stores of the
// block are at the coherence point before thread 0 arrives.
__device__ __forceinline__ void grid_barrier(unsigned* bc1, unsigned* bc2, unsigned* gfl, int idx)
{
  __syncthreads();
  if (threadIdx.x == 0) {
    const unsigned grp = (unsigned)(blockIdx.x >> 4);     // 12 groups x 16 blocks
    unsigned old = __hip_atomic_fetch_add(&bc1[((unsigned)idx * NGRP + grp) * 16u], 1u,
                        __ATOMIC_RELAXED, __HIP_MEMORY_SCOPE_AGENT);
    if (old == 15u) {
      unsigned o2 = __hip_atomic_fetch_add(&bc2[(unsigned)idx * 16u], 1u,
                        __ATOMIC_RELAXED, __HIP_MEMORY_SCOPE_AGENT);
      if (o2 == (unsigned)(NGRP - 1)) {
#pragma unroll
        for (int g = 0; g < NGRP; ++g)
          __hip_atomic_store(&gfl[g * 16], (unsigned)(idx + 1),
                             __ATOMIC_RELAXED, __HIP_MEMORY_SCOPE_AGENT);
      }
    }
    while (__hip_atomic_load(&gfl[grp * 16], __ATOMIC_RELAXED, __HIP_MEMORY_SCOPE_AGENT)
           < (unsigned)(idx + 1))
      __builtin_amdgcn_s_sleep(4);
  }
  __syncthreads();
}

// 512-long row dot against an LDS vector (all lanes read same LDS addr => broadcast)
__device__ __forceinline__ float mv512(const float* __restrict__ wrow, const float* v)
{
  float s = 0.f;
  const float4* wp = (const float4*)wrow;
  const float4* vp = (const float4*)v;
#pragma unroll 8
  for (int k = 0; k < 128; ++k) {
    float4 w4 = wp[k]; float4 v4 = vp[k];
    s += w4.x*v4.x + w4.y*v4.y + w4.z*v4.z + w4.w*v4.w;
  }
  return s;
}

// ---------------- GI0 = x @ Wih0^T + bih0, layout [t][j][b] ----------------
__global__ __launch_bounds__(256) void gi0_gemm(const float* __restrict__ x,
                                                const float* __restrict__ Wih0,
                                                const float* __restrict__ bih0,
                                                float* __restrict__ GI0)
{
  const int t  = blockIdx.x;
  const int j0 = blockIdx.y * 128;
  const int tid = threadIdx.x;
  const int b = tid & 31, u = tid >> 5;

  __shared__ float xs[128][33];
  float acc[16];
#pragma unroll
  for (int jj = 0; jj < 16; jj++) acc[jj] = 0.f;

  for (int kbv = 0; kbv < Dd; kbv += 128) {
    __syncthreads();
    {
      int bb = tid >> 3, kg = (tid & 7) * 4;
      const float* xp = x + ((size_t)bb * Tt + t) * Dd + kbv;
#pragma unroll
      for (int q = 0; q < 4; q++) {
        float4 v = *(const float4*)(xp + kg + q * 32);
        int k = kg + q * 32;
        xs[k + 0][bb] = v.x; xs[k + 1][bb] = v.y;
        xs[k + 2][bb] = v.z; xs[k + 3][bb] = v.w;
      }
    }
    __syncthreads();
    for (int kk = 0; kk < 128; kk += 4) {
      float x0 = xs[kk][b], x1 = xs[kk + 1][b], x2 = xs[kk + 2][b], x3 = xs[kk + 3][b];
#pragma unroll
      for (int jj = 0; jj < 16; jj++) {
        const float* wp = Wih0 + (size_t)(j0 + u + 8 * jj) * Dd + kbv + kk;
        float4 w4 = *(const float4*)wp;
        acc[jj] += w4.x * x0 + w4.y * x1 + w4.z * x2 + w4.w * x3;
      }
    }
  }
#pragma unroll
  for (int jj = 0; jj < 16; jj++) {
    int j = j0 + u + 8 * jj;
    GI0[((size_t)t * G3 + j) * 32 + b] = acc[jj] + bih0[j];
  }
}

// ---------------- persistent HRNN kernel: 3 barriers/step ----------------
// blocks [0,128):   row-blocks, 4 rows per gate-group (i0 = blk*4)
// blocks [128,160): m0-tail per batch: m0b = relu(mW2_0 @ m0a), p0   (P3)
// blocks [160,192): m1-chain per batch: m1a -> m1b -> p1 from cell1  (P3)
__global__ __launch_bounds__(NTHR, 1) void hrnn_persist(
    const float* __restrict__ Whh0, const float* __restrict__ bhh0,
    const float* __restrict__ Wih,  const float* __restrict__ Whh,
    const float* __restrict__ bih,  const float* __restrict__ bhh,
    const float* __restrict__ mW1,  const float* __restrict__ mb1,
    const float* __restrict__ mW2,  const float* __restrict__ mb2,
    const float* __restrict__ mW3,  const float* __restrict__ mb3,
    const float* __restrict__ GI0,
    float* __restrict__ c0R, float* __restrict__ c1R, float* __restrict__ c2R,
    float* __restrict__ m0aR, float* __restrict__ pbuf,
    unsigned* __restrict__ bc1, unsigned* __restrict__ bc2, unsigned* __restrict__ gfl,
    float* __restrict__ out)
{
  __shared__ float red[16][576];
  __shared__ float s_pre[12][32];   // layer0: gh0(+bias,+GI0 r/z) rows [g*4+ii]
  __shared__ float s_gh1[12][32];   // layer1 gh (+bhh)
  __shared__ float s_gh2[12][32];   // layer2 gh (+bhh)
  __shared__ float s_gi[12][32];    // gi of current phase
  __shared__ float s_ab[7][32];     // a0,a1,a2,w10,w11,p0,p1
  __shared__ __align__(16) float hv[512];    // MLP input vector (m-blocks)
  __shared__ __align__(16) float ma[512];    // m1a (m1-chain block)
  __shared__ float rbuf[512];                // p-reduction scratch (m-blocks)

  const int tid = threadIdx.x;
  const int b = tid & 31;
  const int u = tid >> 5;          // 0..15
  const int kb = u * 32;
  const bool isrow = (blockIdx.x < RB);
  const int i0 = (blockIdx.x & (RB - 1)) * 4;
  const int mrole = ((int)blockIdx.x - RB) >> 5;   // 0: m0-tail, 1: m1-chain
  const int mbb   = ((int)blockIdx.x - RB) & 31;   // batch for m-blocks
  int baridx = 0;

  for (int t = 0; t < Tt; t++) {
    const size_t wo = (size_t)(t & (PR - 1)) * HB;
    const size_t ro = (size_t)((t + PR - 1) & (PR - 1)) * HB;
    const float* c0o = c0R + ro;
    const float* c1o = c1R + ro;
    const float* c2o = c2R + ro;

    // ---- p-phase: read p0/p1 of step t-1 (64 floats from MALL), softmax weights ----
    // t=0: pbuf zeroed -> weights arbitrary, multiplied by zeroed ring state (exact).
    if (tid < 64) {
      int which = tid >> 5, b2 = tid & 31;
      s_ab[5 + which][b2] = dload(&pbuf[which * 32 + b2]);
    }
    __syncthreads();
    if (tid < 32) {
      float p0 = s_ab[5][tid], p1 = s_ab[6][tid];
      float e0 = expf(1.f - p0), e1 = expf(p0 * (1.f - p1)), e2 = expf(p0 * p1);
      float inv = 1.f / (e0 + e1 + e2);
      s_ab[0][tid] = e0 * inv; s_ab[1][tid] = e1 * inv; s_ab[2][tid] = e2 * inv;
      float q0 = expf(1.f - p1), q1 = expf(p1);
      float qi = 1.f / (q0 + q1);
      s_ab[3][tid] = q0 * qi; s_ab[4][tid] = q1 * qi;
    }
    __syncthreads();
    const float a0 = s_ab[0][b], a1 = s_ab[1][b], a2 = s_ab[2][b];
    const float w10 = s_ab[3][b], w11 = s_ab[4][b];

    // ---- P1: gh0/gh1/gh2 with inline h-mixing; cell0 ----
    if (isrow) {
      float acc[36];
#pragma unroll
      for (int w = 0; w < 36; w++) acc[w] = 0.f;
      for (int kk = 0; kk < 32; kk += 4) {
        float mh0[4], mh1[4], vv2[4];
#pragma unroll
        for (int q = 0; q < 4; q++) {
          int k = kb + kk + q;
          float v0 = c0o[k * 32 + b], v1 = c1o[k * 32 + b], v2 = c2o[k * 32 + b];
          vv2[q] = v2;
          mh0[q] = a0 * v0 + a1 * v1 + a2 * v2;
          mh1[q] = w10 * v1 + w11 * v2;
        }
#pragma unroll
        for (int w = 0; w < 36; w++) {
          const int l = w / 12, rem = w % 12;
          const int row = (rem >> 2) * 512 + i0 + (rem & 3);
          const float* wp = (l == 0) ? (Whh0 + (size_t)row * 512)
                          : (l == 1) ? (Whh  + (size_t)row * 512)
                                     : (Whh  + (size_t)(G3 + row) * 512);
          float4 w4 = *(const float4*)(wp + kb + kk);
          acc[w] += dot4f(w4, (l == 0) ? mh0 : (l == 1) ? mh1 : vv2);
        }
      }
      // two-round LDS reduction (36 rows won't fit red[] in one round)
#pragma unroll
      for (int w = 0; w < 18; w++) red[u][w * 32 + b] = acc[w];
      __syncthreads();
      for (int o = tid; o < 18 * 32; o += NTHR) {
        float s = 0.f;
#pragma unroll
        for (int uu = 0; uu < 16; uu++) s += red[uu][o];
        int w = o >> 5, b2 = o & 31;
        int l = w / 12, rem = w % 12;
        int row = (rem >> 2) * 512 + i0 + (rem & 3);
        if (l == 0) {
          s += bhh0[row];
          if (rem < 8) s += GI0[((size_t)t * G3 + row) * 32 + b2];
          s_pre[rem][b2] = s;
        } else {
          s_gh1[rem][b2] = s + bhh[row];
        }
      }
      __syncthreads();
#pragma unroll
      for (int w = 18; w < 36; w++) red[u][(w - 18) * 32 + b] = acc[w];
      __syncthreads();
      for (int o = tid; o < 18 * 32; o += NTHR) {
        float s = 0.f;
#pragma unroll
        for (int uu = 0; uu < 16; uu++) s += red[uu][o];
        int w = (o >> 5) + 18, b2 = o & 31;
        int l = w / 12, rem = w % 12;
        int row = (rem >> 2) * 512 + i0 + (rem & 3);
        if (l == 1) s_gh1[rem][b2] = s + bhh[row];
        else        s_gh2[rem][b2] = s + bhh[G3 + row];
      }
      __syncthreads();
      if (tid < 128) {
        int ii = tid >> 5, bb = tid & 31;
        float r = sigf(s_pre[ii][bb]);
        float z = sigf(s_pre[4 + ii][bb]);
        float inn = GI0[((size_t)t * G3 + 1024 + i0 + ii) * 32 + bb];
        float n = tanhf(inn + r * s_pre[8 + ii][bb]);
        int idx = (i0 + ii) * 32 + bb;
        float h0old = a0 * c0o[idx] + a1 * c1o[idx] + a2 * c2o[idx];
        dstore(&c0R[wo + idx], (1.f - z) * n + z * h0old);
      }
    }
    grid_barrier(bc1, bc2, gfl, baridx++);

    // ---- P2: gi1 (over cell0) + m0a rows; cell1 ----
    if (isrow) {
      const float* c0n = c0R + wo;
      float acc[16];
#pragma unroll
      for (int w = 0; w < 16; w++) acc[w] = 0.f;
      for (int kk = 0; kk < 32; kk += 4) {
        float v[4];
#pragma unroll
        for (int q = 0; q < 4; q++) v[q] = c0n[(kb + kk + q) * 32 + b];
#pragma unroll
        for (int w = 0; w < 16; w++) {
          const float* wp = (w < 12) ? (Wih + (size_t)((w >> 2) * 512 + i0 + (w & 3)) * 512)
                                     : (mW1 + (size_t)(i0 + (w - 12)) * 512);
          float4 w4 = *(const float4*)(wp + kb + kk);
          acc[w] += dot4f(w4, v);
        }
      }
#pragma unroll
      for (int w = 0; w < 16; w++) red[u][w * 32 + b] = acc[w];
      __syncthreads();
      {
        float s = 0.f;
#pragma unroll
        for (int uu = 0; uu < 16; uu++) s += red[uu][tid];
        int w = tid >> 5, b2 = tid & 31;
        if (w < 12) {
          int row = (w >> 2) * 512 + i0 + (w & 3);
          s_gi[w][b2] = s + bih[row];
        } else {
          int col = i0 + (w - 12);
          dstore(&m0aR[wo + col * 32 + b2], fmaxf(s + mb1[col], 0.f));
        }
      }
      __syncthreads();
      if (tid < 128) {
        int ii = tid >> 5, bb = tid & 31;
        float r = sigf(s_gi[ii][bb] + s_gh1[ii][bb]);
        float z = sigf(s_gi[4 + ii][bb] + s_gh1[4 + ii][bb]);
        float n = tanhf(s_gi[8 + ii][bb] + r * s_gh1[8 + ii][bb]);
        int idx = (i0 + ii) * 32 + bb;
        float h1old = w10 * c1o[idx] + w11 * c2o[idx];
        dstore(&c1R[wo + idx], (1.f - z) * n + z * h1old);
      }
    }
    grid_barrier(bc1, bc2, gfl, baridx++);

    // ---- P3: row-blocks: gi2 (over cell1) + cell2.  m-blocks: MLP tails -> p0/p1 ----
    if (isrow) {
      const float* c1n = c1R + wo;
      float acc[12];
#pragma unroll
      for (int w = 0; w < 12; w++) acc[w] = 0.f;
      for (int kk = 0; kk < 32; kk += 4) {
        float v[4];
#pragma unroll
        for (int q = 0; q < 4; q++) v[q] = c1n[(kb + kk + q) * 32 + b];
#pragma unroll
        for (int w = 0; w < 12; w++) {
          const float* wp = Wih + (size_t)(G3 + (w >> 2) * 512 + i0 + (w & 3)) * 512;
          float4 w4 = *(const float4*)(wp + kb + kk);
          acc[w] += dot4f(w4, v);
        }
      }
#pragma unroll
      for (int w = 0; w < 12; w++) red[u][w * 32 + b] = acc[w];
      __syncthreads();
      if (tid < 384) {
        float s = 0.f;
#pragma unroll
        for (int uu = 0; uu < 16; uu++) s += red[uu][tid];
        int w = tid >> 5, b2 = tid & 31;
        int row = (w >> 2) * 512 + i0 + (w & 3);
        s_gi[w][b2] = s + bih[G3 + row];
      }
      __syncthreads();
      if (tid < 128) {
        int ii = tid >> 5, bb = tid & 31;
        float r = sigf(s_gi[ii][bb] + s_gh2[ii][bb]);
        float z = sigf(s_gi[4 + ii][bb] + s_gh2[4 + ii][bb]);
        float n = tanhf(s_gi[8 + ii][bb] + r * s_gh2[8 + ii][bb]);
        int idx = (i0 + ii) * 32 + bb;
        dstore(&c2R[wo + idx], (1.f - z) * n + z * c2o[idx]);
      }
    } else {
      // one block per (role,batch): MLP tail is block-local, so no extra grid barrier
      const int j = tid;
      hv[j] = (mrole == 0) ? m0aR[wo + (size_t)j * 32 + mbb]
                           : c1R [wo + (size_t)j * 32 + mbb];
      __syncthreads();
      float v;
      if (mrole == 0) {
        float s = mv512(mW2 + (size_t)j * 512, hv);         // m0b row j
        v = fmaxf(s + mb2[j], 0.f) * mW3[j];
      } else {
        float s = mv512(mW1 + (size_t)(512 + j) * 512, hv); // m1a row j
        ma[j] = fmaxf(s + mb1[512 + j], 0.f);
        __syncthreads();
        float s2 = mv512(mW2 + (size_t)(512 + j) * 512, ma); // m1b row j
        v = fmaxf(s2 + mb2[512 + j], 0.f) * mW3[512 + j];
      }
      rbuf[j] = v;
      __syncthreads();
      if (tid < 64) {
        float s = 0.f;
#pragma unroll
        for (int q = 0; q < 8; q++) s += rbuf[tid + 64 * q];
#pragma unroll
        for (int off = 32; off; off >>= 1) s += __shfl_down(s, off);
        if (tid == 0) {
          float p = sigf(s + mb3[mrole]);
          dstore(&pbuf[mrole * 32 + mbb], p);
          out[((size_t)mbb * Tt + t) * 2 + mrole] = p;
        }
      }
    }
    grid_barrier(bc1, bc2, gfl, baridx++);
  }
}

extern "C" void kernel_launch(void* const* d_in, const int* in_sizes, int n_in,
                              void* d_out, int out_size, void* d_ws, size_t ws_size,
                              hipStream_t stream)
{
  (void)in_sizes; (void)n_in; (void)out_size;
  const float* x    = (const float*)d_in[0];
  const float* Wih0 = (const float*)d_in[1];
  const float* Whh0 = (const float*)d_in[2];
  const float* bih0 = (const float*)d_in[3];
  const float* bhh0 = (const float*)d_in[4];
  const float* Wih  = (const float*)d_in[5];
  const float* Whh  = (const float*)d_in[6];
  const float* bih  = (const float*)d_in[7];
  const float* bhh  = (const float*)d_in[8];
  const float* mW1  = (const float*)d_in[9];
  const float* mb1  = (const float*)d_in[10];
  const float* mW2  = (const float*)d_in[11];
  const float* mb2  = (const float*)d_in[12];
  const float* mW3  = (const float*)d_in[13];
  const float* mb3  = (const float*)d_in[14];
  float* out = (float*)d_out;

  char* ws = (char*)d_ws;
  size_t off = 0;
  auto take = [&](size_t bytes) { size_t o = off; off = (off + bytes + 255) & ~(size_t)255; return o; };
  unsigned* bc1 = (unsigned*)(ws + take((size_t)NBAR * NGRP * 16 * 4));
  unsigned* bc2 = (unsigned*)(ws + take((size_t)NBAR * 16 * 4));
  unsigned* gfl = (unsigned*)(ws + take((size_t)16 * 16 * 4));
  float* c0R  = (float*)(ws + take((size_t)PR * HB * 4));
  float* c1R  = (float*)(ws + take((size_t)PR * HB * 4));
  float* c2R  = (float*)(ws + take((size_t)PR * HB * 4));
  float* m0aR = (float*)(ws + take((size_t)PR * HB * 4));
  float* pbuf = (float*)(ws + take((size_t)64 * 4));
  size_t zero_bytes = off;
  float* GI0 = (float*)(ws + take((size_t)Tt * G3 * Bb * 4));
  if (ws_size < off) return;  // fail visibly rather than corrupt

  hipMemsetAsync(d_ws, 0, zero_bytes, stream);
  gi0_gemm<<<dim3(Tt, G3 / 128), 256, 0, stream>>>(x, Wih0, bih0, GI0);
  hrnn_persist<<<NBLK, NTHR, 0, stream>>>(Whh0, bhh0, Wih, Whh, bih, bhh,
      mW1, mb1, mW2, mb2, mW3, mb3, GI0,
      c0R, c1R, c2R, m0aR, pbuf, bc1, bc2, gfl, out);
}